// Round 1
// baseline (555.859 us; speedup 1.0000x reference)
//
#include <hip/hip_runtime.h>
#include <hip/hip_bf16.h>
#include <stdint.h>

// ---------------------------------------------------------------------------
// TFEfficientFormerSelfAttention  (B=256, S=256, DIM=448, H=8, KD=32, EKD=128)
// Pipeline: [convert/transpose/bias-gather] -> QKV GEMM (bf16 MFMA, scatter
// epilogue to Q/K/Vt layouts) -> per-(b,h) fused attention -> proj GEMM.
// All MFMA uses verified gfx950 16x16x32 bf16 fragment layouts:
//   A: row=l&15, k=(l>>4)*8+j ; B: col=l&15, k=(l>>4)*8+j ;
//   D: col=l&15, row=(l>>4)*4+r  (m89/m91).
// ---------------------------------------------------------------------------

typedef __attribute__((ext_vector_type(4))) float f32x4;
typedef __attribute__((ext_vector_type(8))) short short8;
typedef __attribute__((ext_vector_type(4))) unsigned short u16x4;

#define DEVINL static __device__ __forceinline__

DEVINL unsigned short f2bf(float f) {
  unsigned u = __float_as_uint(f);
  return (unsigned short)((u + 0x7FFFu + ((u >> 16) & 1u)) >> 16);
}
DEVINL float bf2f(short s) {
  return __uint_as_float(((unsigned)(unsigned short)s) << 16);
}

DEVINL void gload_lds16(const void* g, void* l) {
  __builtin_amdgcn_global_load_lds((const __attribute__((address_space(1))) void*)g,
                                   (__attribute__((address_space(3))) void*)l,
                                   16, 0, 0);
}

#define SCALE 0.17677669529663687f

// ---------------- workspace layout (bytes) ----------------
// region0 : Xb (56MB) during QKV GEMM, then CTX (128MB) overlays it
#define WS_XB    ((size_t)0)
#define WS_CTX   ((size_t)0)
#define WS_WQT   ((size_t)134217728)   // 1536x448 bf16
#define WS_WPT   ((size_t)135593984)   // 512x1024 bf16 (padded rows 448..511 = 0)
#define WS_QW    ((size_t)136642560)   // [2048][256][32] bf16
#define WS_KW    ((size_t)170196992)   // [2048][256][32] bf16
#define WS_VT    ((size_t)203751424)   // [2048][128][264] bf16 (s padded 256->264)
#define WS_BIAS  ((size_t)342163456)   // [8][256][256] f32
// total = 344,260,608 bytes

// ---------------- prep kernels ----------------

__global__ void k_convert_x(const float* __restrict__ x, short* __restrict__ xb) {
  const size_t i = (size_t)blockIdx.x * blockDim.x + threadIdx.x;  // 8 elems each
  const f32x4* src = (const f32x4*)x + i * 2;
  f32x4 a = src[0], b = src[1];
  short8 o;
#pragma unroll
  for (int t = 0; t < 4; ++t) o[t] = (short)f2bf(a[t]);
#pragma unroll
  for (int t = 0; t < 4; ++t) o[4 + t] = (short)f2bf(b[t]);
  ((short8*)xb)[i] = o;
}

// out[n][k] = in[k][n] (bf16), rows n>=N are zero (pad)
__global__ void k_transpose_bf16(const float* __restrict__ in, short* __restrict__ out,
                                 int K, int N, int total) {
  const int idx = blockIdx.x * blockDim.x + threadIdx.x;
  if (idx >= total) return;
  const int n = idx / K, k = idx - n * K;
  const float v = (n < N) ? in[(size_t)k * N + n] : 0.0f;
  out[idx] = (short)f2bf(v);
}

__global__ void k_bias_gather(const float* __restrict__ biases, const int* __restrict__ idxs,
                              float* __restrict__ outb, int n_off) {
  const int i = blockIdx.x * blockDim.x + threadIdx.x;  // < 524288
  const int h = i >> 16, p = i & 65535;
  outb[i] = biases[h * n_off + idxs[p]];
}

// ---------------- shared 128x128 GEMM mainloop (m97 structure) ----------------

template <int KSTEPS, int LDA, int LDB>
DEVINL void gemm128_body(const short* __restrict__ A, const short* __restrict__ B,
                         short* Asm, short* Bsm, int m0, int n0, int tid,
                         f32x4 acc[4][4]) {
  const int lane = tid & 63, wave = tid >> 6;
  const int l15 = lane & 15, g = lane >> 4;
  const int wm = wave >> 1, wn = wave & 1;
  const int srow = wave * 32 + (lane >> 2);
  const int scol = (lane & 3) * 8;
  for (int ks = 0; ks < KSTEPS; ++ks) {
    const int k0 = ks * 32;
#pragma unroll
    for (int c = 0; c < 2; ++c) {
      gload_lds16(A + (size_t)(m0 + srow + c * 16) * LDA + k0 + scol,
                  Asm + wave * 1024 + c * 512);
      gload_lds16(B + (size_t)(n0 + srow + c * 16) * LDB + k0 + scol,
                  Bsm + wave * 1024 + c * 512);
    }
    __syncthreads();
    short8 a[4], b[4];
#pragma unroll
    for (int i = 0; i < 4; ++i)
      a[i] = *(const short8*)(Asm + (wm * 64 + i * 16 + l15) * 32 + g * 8);
#pragma unroll
    for (int j = 0; j < 4; ++j)
      b[j] = *(const short8*)(Bsm + (wn * 64 + j * 16 + l15) * 32 + g * 8);
#pragma unroll
    for (int i = 0; i < 4; ++i)
#pragma unroll
      for (int j = 0; j < 4; ++j)
        acc[i][j] = __builtin_amdgcn_mfma_f32_16x16x32_bf16(a[i], b[j], acc[i][j], 0, 0, 0);
    __syncthreads();
  }
}

// ---------------- QKV GEMM: Xb[65536][448] @ Wt^T -> scatter Q/K/Vt ----------------

__global__ __launch_bounds__(256) void k_qkv_gemm(
    const short* __restrict__ Xb, const short* __restrict__ Wt,
    const float* __restrict__ qkvb,
    short* __restrict__ Qw, short* __restrict__ Kw, short* __restrict__ Vt) {
  __shared__ short Asm[4096], Bsm[4096];
  const int tid = threadIdx.x;
  const int m0 = blockIdx.x * 128, n0 = blockIdx.y * 128;
  f32x4 acc[4][4];
#pragma unroll
  for (int i = 0; i < 4; ++i)
#pragma unroll
    for (int j = 0; j < 4; ++j) acc[i][j] = (f32x4){0.f, 0.f, 0.f, 0.f};

  gemm128_body<14, 448, 448>(Xb, Wt, Asm, Bsm, m0, n0, tid, acc);

  const int lane = tid & 63, wave = tid >> 6;
  const int l15 = lane & 15, g = lane >> 4;
  const int wm = wave >> 1, wn = wave & 1;
#pragma unroll
  for (int i = 0; i < 4; ++i) {
    const int mb = m0 + wm * 64 + i * 16 + g * 4;  // 4 consecutive rows mb..mb+3
    const int bb = mb >> 8, s0 = mb & 255;
#pragma unroll
    for (int j = 0; j < 4; ++j) {
      const int n = n0 + wn * 64 + j * 16 + l15;
      const float bv = qkvb[n];
      const int h = n / 192;
      const int c = n - h * 192;
      const int bh = bb * 8 + h;
      if (c >= 64) {
        const int e = c - 64;
        u16x4 pk;
#pragma unroll
        for (int r = 0; r < 4; ++r) pk[r] = f2bf(acc[i][j][r] + bv);
        *(u16x4*)(Vt + (size_t)bh * 33792 + e * 264 + s0) = pk;  // 8B store
      } else {
        short* dst = (c < 32) ? Qw : Kw;
        const int d = c & 31;
        const size_t base = ((size_t)bh * 256 + s0) * 32 + d;
#pragma unroll
        for (int r = 0; r < 4; ++r) dst[base + (size_t)r * 32] = (short)f2bf(acc[i][j][r] + bv);
      }
    }
  }
}

// ---------------- fused attention per (b,h) ----------------
// LDS: Q[256][32] K[256][32] V[128][264] P[32][264] (bf16) + rinv[32] = 117.5KB

__global__ __launch_bounds__(512) void k_attn(
    const short* __restrict__ Qw, const short* __restrict__ Kw,
    const short* __restrict__ Vt, const float* __restrict__ Bias,
    short* __restrict__ CTX) {
  __shared__ short Qs[8192];
  __shared__ short Ks[8192];
  __shared__ short Vs[128 * 264];
  __shared__ short Ps[32 * 264];
  __shared__ float rinv[32];

  const int tid = threadIdx.x, lane = tid & 63, wave = tid >> 6;  // 8 waves
  const int l15 = lane & 15, g = lane >> 4;
  const int bh = blockIdx.x;
  const int b = bh >> 3, h = bh & 7;

  // stage Q (16 chunks), K (16), V (66) of 1KB each, all linear
  {
    const short* Qsrc = Qw + (size_t)bh * 8192;
    const short* Ksrc = Kw + (size_t)bh * 8192;
    const short* Vsrc = Vt + (size_t)bh * 33792;
    for (int c = wave; c < 98; c += 8) {
      const short* src;
      short* dst;
      if (c < 16)      { src = Qsrc + c * 512;        dst = &Qs[c * 512]; }
      else if (c < 32) { src = Ksrc + (c - 16) * 512; dst = &Ks[(c - 16) * 512]; }
      else             { src = Vsrc + (c - 32) * 512; dst = &Vs[(c - 32) * 512]; }
      gload_lds16(src + lane * 8, dst);
    }
  }
  __syncthreads();

  const float* biasH = Bias + (size_t)h * 65536;

  for (int qb = 0; qb < 8; ++qb) {
    const int q0 = qb * 32;
    // ---- scores: this wave covers kk in [wave*32, wave*32+32) ----
    short8 aq[2];
#pragma unroll
    for (int i = 0; i < 2; ++i)
      aq[i] = *(const short8*)&Qs[(q0 + i * 16 + l15) * 32 + g * 8];
#pragma unroll
    for (int fj = 0; fj < 2; ++fj) {
      const int kk0 = wave * 32 + fj * 16;
      const short8 bk = *(const short8*)&Ks[(kk0 + l15) * 32 + g * 8];
      const int kk = kk0 + l15;
#pragma unroll
      for (int i = 0; i < 2; ++i) {
        f32x4 sc = (f32x4){0.f, 0.f, 0.f, 0.f};
        sc = __builtin_amdgcn_mfma_f32_16x16x32_bf16(aq[i], bk, sc, 0, 0, 0);
        const int qrow0 = i * 16 + g * 4;
#pragma unroll
        for (int r = 0; r < 4; ++r) {
          const int qrow = qrow0 + r;
          const float logit = sc[r] * SCALE + biasH[(q0 + qrow) * 256 + kk];
          Ps[qrow * 264 + kk] = (short)f2bf(logit);
        }
      }
    }
    __syncthreads();

    // ---- softmax: 512 threads = 32 rows x 16 parts (16 values each) ----
    {
      const int r = tid >> 4, part = tid & 15;
      short8 x0 = ((const short8*)&Ps[r * 264 + part * 16])[0];
      short8 x1 = ((const short8*)&Ps[r * 264 + part * 16])[1];
      float v[16];
#pragma unroll
      for (int t = 0; t < 8; ++t) { v[t] = bf2f(x0[t]); v[8 + t] = bf2f(x1[t]); }
      float mx = v[0];
#pragma unroll
      for (int t = 1; t < 16; ++t) mx = fmaxf(mx, v[t]);
#pragma unroll
      for (int d = 1; d < 16; d <<= 1) mx = fmaxf(mx, __shfl_xor(mx, d));
      float sum = 0.f;
#pragma unroll
      for (int t = 0; t < 16; ++t) { v[t] = __expf(v[t] - mx); sum += v[t]; }
#pragma unroll
      for (int d = 1; d < 16; d <<= 1) sum += __shfl_xor(sum, d);
      short8 o0, o1;
#pragma unroll
      for (int t = 0; t < 8; ++t) { o0[t] = (short)f2bf(v[t]); o1[t] = (short)f2bf(v[8 + t]); }
      ((short8*)&Ps[r * 264 + part * 16])[0] = o0;
      ((short8*)&Ps[r * 264 + part * 16])[1] = o1;
      if (part == 0) rinv[r] = 1.0f / sum;
    }
    __syncthreads();

    // ---- PV: this wave covers e in [wave*16, wave*16+16) ----
    {
      f32x4 cacc[2] = {(f32x4){0.f, 0.f, 0.f, 0.f}, (f32x4){0.f, 0.f, 0.f, 0.f}};
      const int e = wave * 16 + l15;
#pragma unroll
      for (int kstep = 0; kstep < 8; ++kstep) {
        const short8 bv = *(const short8*)&Vs[e * 264 + kstep * 32 + g * 8];
#pragma unroll
        for (int i = 0; i < 2; ++i) {
          const short8 ap = *(const short8*)&Ps[(i * 16 + l15) * 264 + kstep * 32 + g * 8];
          cacc[i] = __builtin_amdgcn_mfma_f32_16x16x32_bf16(ap, bv, cacc[i], 0, 0, 0);
        }
      }
#pragma unroll
      for (int i = 0; i < 2; ++i) {
        const int qrow0 = i * 16 + g * 4;
#pragma unroll
        for (int r = 0; r < 4; ++r) {
          const int s = q0 + qrow0 + r;
          const float val = cacc[i][r] * rinv[qrow0 + r];
          CTX[((size_t)b * 256 + s) * 1024 + h * 128 + e] = (short)f2bf(val);
        }
      }
    }
    __syncthreads();
  }
}

// ---------------- proj GEMM: CTX[65536][1024] @ WptT -> out f32 ----------------

__global__ __launch_bounds__(256) void k_proj_gemm(
    const short* __restrict__ CTX, const short* __restrict__ Wpt,
    const float* __restrict__ projb, float* __restrict__ out) {
  __shared__ short Asm[4096], Bsm[4096];
  const int tid = threadIdx.x;
  const int m0 = blockIdx.x * 128, n0 = blockIdx.y * 128;
  f32x4 acc[4][4];
#pragma unroll
  for (int i = 0; i < 4; ++i)
#pragma unroll
    for (int j = 0; j < 4; ++j) acc[i][j] = (f32x4){0.f, 0.f, 0.f, 0.f};

  gemm128_body<32, 1024, 1024>(CTX, Wpt, Asm, Bsm, m0, n0, tid, acc);

  const int lane = tid & 63, wave = tid >> 6;
  const int l15 = lane & 15, g = lane >> 4;
  const int wm = wave >> 1, wn = wave & 1;
#pragma unroll
  for (int i = 0; i < 4; ++i) {
    const int mb = m0 + wm * 64 + i * 16 + g * 4;
#pragma unroll
    for (int j = 0; j < 4; ++j) {
      const int n = n0 + wn * 64 + j * 16 + l15;
      if (n < 448) {
        const float bv = projb[n];
#pragma unroll
        for (int r = 0; r < 4; ++r)
          out[(size_t)(mb + r) * 448 + n] = acc[i][j][r] + bv;
      }
    }
  }
}

// ---------------- launch ----------------

extern "C" void kernel_launch(void* const* d_in, const int* in_sizes, int n_in,
                              void* d_out, int out_size, void* d_ws, size_t ws_size,
                              hipStream_t stream) {
  const float* X      = (const float*)d_in[0];
  const float* qkv_w  = (const float*)d_in[1];
  const float* qkv_b  = (const float*)d_in[2];
  const float* proj_w = (const float*)d_in[3];
  const float* proj_b = (const float*)d_in[4];
  const float* att_b  = (const float*)d_in[5];
  const int*   attidx = (const int*)d_in[6];
  const int n_off = in_sizes[5] / 8;

  char* ws = (char*)d_ws;
  short* Xb    = (short*)(ws + WS_XB);
  short* CTX   = (short*)(ws + WS_CTX);
  short* WQT   = (short*)(ws + WS_WQT);
  short* WPT   = (short*)(ws + WS_WPT);
  short* Qw    = (short*)(ws + WS_QW);
  short* Kw    = (short*)(ws + WS_KW);
  short* Vt    = (short*)(ws + WS_VT);
  float* BiasF = (float*)(ws + WS_BIAS);

  k_convert_x<<<14336, 256, 0, stream>>>(X, Xb);
  k_transpose_bf16<<<(1536 * 448 + 255) / 256, 256, 0, stream>>>(qkv_w, WQT, 448, 1536, 1536 * 448);
  k_transpose_bf16<<<(512 * 1024 + 255) / 256, 256, 0, stream>>>(proj_w, WPT, 1024, 448, 512 * 1024);
  k_bias_gather<<<2048, 256, 0, stream>>>(att_b, attidx, BiasF, n_off);

  k_qkv_gemm<<<dim3(512, 12), 256, 0, stream>>>(Xb, WQT, qkv_b, Qw, Kw, Vt);
  k_attn<<<2048, 512, 0, stream>>>(Qw, Kw, Vt, BiasF, CTX);
  k_proj_gemm<<<dim3(512, 4), 256, 0, stream>>>(CTX, WPT, proj_b, (float*)d_out);
}